// Round 2
// baseline (115.811 us; speedup 1.0000x reference)
//
#include <hip/hip_runtime.h>

// Problem constants
#define NROWS 8192   // 4 * 2048
#define DIM   512
#define NT    64                    // 8192 / 128 tiles per side
#define NTRI  (NT * (NT + 1) / 2)   // 2080 upper-triangular tile blocks
#define NACC  64                    // accumulator slots (contention spread)

typedef __attribute__((ext_vector_type(16))) float f32x16;
typedef __attribute__((ext_vector_type(8)))  int   i32x8;

// Software fp32 -> OCP e4m3fn, round-to-nearest-even (r7/r8-verified).
__device__ __forceinline__ unsigned char f2e4m3(float x) {
    unsigned ux = __float_as_uint(x);
    unsigned s  = (ux >> 24) & 0x80u;
    float a = __uint_as_float(ux & 0x7FFFFFFFu);     // |x|, finite for our data
    a = fminf(a, 448.0f);                            // clamp to max finite
    unsigned ua = __float_as_uint(a);
    int eb = (int)(ua >> 23);                        // biased exponent
    if (eb < 121) eb = 121;                          // denormal region: step 2^-9
    float step  = __uint_as_float((unsigned)(eb - 3) << 23);    // 2^(eb-130)
    float istep = __uint_as_float((unsigned)(257 - eb) << 23);  // 2^(130-eb), exact
    float q = rintf(a * istep) * step;               // RNE on e4m3 grid
    q = fminf(q, 448.0f);
    if (q < 0.001953125f)                            // below min denormal 2^-9 -> 0
        return (unsigned char)s;
    unsigned uq = __float_as_uint(q);
    int eq = (int)(uq >> 23) - 127;
    unsigned byte;
    if (eq < -6) byte = (unsigned)(q * 512.0f);      // denormal: d*2^-9, d in 1..7
    else         byte = (unsigned)((eq + 7) << 3) | ((uq >> 20) & 7u);
    return (unsigned char)(s | byte);
}

// Kernel 1: fp32 row norms + fp32->fp8 conversion into a pre-swizzled global
// layout. r10: swizzle at 16B granularity — within each 64B k-slab of row r,
// 16B chunk c (0..3) is stored at position c ^ ((r>>1)&3). GEMM frag reads
// are then ds_read_b128 at the conflict-free floor (bank slot = 4*(r&1) +
// pos, bijective in r&7 -> 8 lanes/slot = exactly the 8-phase b128 floor),
// and staging stays a linear global_load_lds copy (rule #21).
__global__ __launch_bounds__(256) void norm_convert_kernel(
    const float* __restrict__ X, unsigned char* __restrict__ Xq,
    float* __restrict__ norms, float* __restrict__ acc)
{
    const int tid  = threadIdx.x;
    const int lane = tid & 63;
    const int w    = tid >> 6;
    const int row  = blockIdx.x * 4 + w;

    if (blockIdx.x == 0 && tid < NACC + 1) acc[tid] = 0.0f;  // +1: done-counter

    const float* xr = X + (size_t)row * DIM + lane * 8;
    float4 v0 = *(const float4*)xr;
    float4 v1 = *(const float4*)(xr + 4);

    float s = 0.0f;
    s = fmaf(v0.x, v0.x, s); s = fmaf(v0.y, v0.y, s);
    s = fmaf(v0.z, v0.z, s); s = fmaf(v0.w, v0.w, s);
    s = fmaf(v1.x, v1.x, s); s = fmaf(v1.y, v1.y, s);
    s = fmaf(v1.z, v1.z, s); s = fmaf(v1.w, v1.w, s);

    union { unsigned char b[8]; uint2 v; } pk;
    pk.b[0] = f2e4m3(v0.x); pk.b[1] = f2e4m3(v0.y);
    pk.b[2] = f2e4m3(v0.z); pk.b[3] = f2e4m3(v0.w);
    pk.b[4] = f2e4m3(v1.x); pk.b[5] = f2e4m3(v1.y);
    pk.b[6] = f2e4m3(v1.z); pk.b[7] = f2e4m3(v1.w);

    const int slab = lane >> 3;                      // 64B slab index (0..7)
    const int c16  = (lane >> 1) & 3;                // 16B chunk in slab
    const int cpos = c16 ^ ((row >> 1) & 3);         // swizzled chunk position
    *(uint2*)(Xq + (size_t)row * DIM + slab * 64 + cpos * 16 + (lane & 1) * 8)
        = pk.v;

    #pragma unroll
    for (int off = 32; off > 0; off >>= 1) s += __shfl_down(s, off, 64);
    if (lane == 0) norms[row] = s;
}

// Async global->LDS DMA, 16B/lane (dest = wave-uniform base + lane*16;
// global source IS per-lane -> swizzled layouts via pre-swizzled source).
__device__ __forceinline__ void gload16(const void* g, void* l) {
    __builtin_amdgcn_global_load_lds(
        (const __attribute__((address_space(1))) unsigned int*)g,
        (__attribute__((address_space(3))) unsigned int*)l, 16, 0, 0);
}

// Kernel 2: upper-triangular tiled X·X^T (MX fp8, unit scales) + fused
// sqrt/exp/sum epilogue + fused last-block finalize.
//
// r10 structural fix (r9 post-mortem: one 32x32x64 scaled MFMA = ~69 cyc,
// so BK=64 gave only 275 cyc of compute per barrier -> every prefetch's
// vmcnt(0)-before-barrier drain was exposed; MfmaUtil 13%):
//   BK=128, double-buffered: 8 MFMA (~550 cyc) per barrier window >= load
//   latency -> drain hidden; barrier count 8 -> 4. LDS 2*(16K A + 16K B) =
//   64KB -> 2 blocks/CU, anti-phase overlap of DMA vs MFMA across blocks.
//   Frag reads: ds_read_b128 pairs at 16B-swizzled positions (conflict-free
//   floor, see kernel-1 comment). Staging: 8 gload16/wave/step, lane-linear
//   LDS dest (conflict-free by construction).
// NO device-scope fences (r3: agent fence = per-XCD L2 flush, +40us);
// finalize ordering via atomic-return data dependency instead.
__global__ __launch_bounds__(256, 2) void pair_loss_gemm_kernel(
    const unsigned char* __restrict__ Xq, const float* __restrict__ norms,
    float* __restrict__ acc, float* __restrict__ out)
{
    // LDS layout per buffer: [sub-slab s:2][row:128][64B], rows 64B-strided
    __shared__ __align__(16) char As0[16384];
    __shared__ __align__(16) char As1[16384];
    __shared__ __align__(16) char Bs0[16384];
    __shared__ __align__(16) char Bs1[16384];
    __shared__ float wsum[4];
    __shared__ int lastflag;

    // decode linear block id -> upper-triangular (bi, bj), bi <= bj
    int t = blockIdx.x, bi = 0;
    while (t >= (NT - bi)) { t -= (NT - bi); bi++; }
    const int bj = bi + t;

    const int tid  = threadIdx.x;
    const int lane = tid & 63;
    const int w    = tid >> 6;

    const int rowA = bi * 128;
    const int rowB = bj * 128;

    f32x16 accv[2][2];
    #pragma unroll
    for (int a = 0; a < 2; a++)
        #pragma unroll
        for (int b = 0; b < 2; b++)
            #pragma unroll
            for (int r = 0; r < 16; r++) accv[a][b][r] = 0.0f;

    // staging sources: wave w stages rows [w*32, w*32+32) of both tiles.
    // lane covers row lrow = lane>>2 of a 16-row group, 16B chunk lane&3 at
    // swizzled global position (lane&3)^((lane>>3)&3) (= (row>>1)&3 key).
    const int lrow = lane >> 2;
    const int lpos = ((lane & 3) ^ ((lane >> 3) & 3)) * 16;
    const unsigned char* gA =
        Xq + (size_t)(rowA + w * 32 + lrow) * DIM + lpos;
    const unsigned char* gB =
        Xq + (size_t)(rowB + w * 32 + lrow) * DIM + lpos;
    char* const ldst0 = (char*)0 + (w * 32) * 64;        // dest offsets
    // per step k: {s=0,1} x {g=0,1}: src += g*16*DIM + s*64 + k*128
    //             dst = buf + s*8192 + (w*32+g*16)*64

    // MFMA frag addressing: row rl = lane&31, k-half qh = lane>>5 (32B =
    // two 16B chunks 2qh, 2qh+1 at swizzled positions ^((rl>>1)&3)).
    const int rl = lane & 31;
    const int qh = lane >> 5;
    const int p0 = ((2 * qh) ^ ((rl >> 1) & 3)) * 16;    // j=0 byte pos
    const int p1 = p0 ^ 16;                              // j=1 byte pos
    const int wr = (w & 1) * 64;
    const int wc = (w >> 1) * 64;
    const int ra = (wr + rl) * 64;                       // a=0 row offset
    const int rb = (wc + rl) * 64;                       // b=0 row offset

#define STAGE(bufA, bufB, k) do {                                        \
        const int kb_ = (k) * 128;                                       \
        gload16(gA + kb_,             (bufA) + (w * 32) * 64);           \
        gload16(gA + kb_ + 16 * DIM,  (bufA) + (w * 32 + 16) * 64);      \
        gload16(gA + kb_ + 64,        (bufA) + 8192 + (w * 32) * 64);    \
        gload16(gA + kb_ + 16 * DIM + 64,                                \
                (bufA) + 8192 + (w * 32 + 16) * 64);                     \
        gload16(gB + kb_,             (bufB) + (w * 32) * 64);           \
        gload16(gB + kb_ + 16 * DIM,  (bufB) + (w * 32 + 16) * 64);      \
        gload16(gB + kb_ + 64,        (bufB) + 8192 + (w * 32) * 64);    \
        gload16(gB + kb_ + 16 * DIM + 64,                                \
                (bufB) + 8192 + (w * 32 + 16) * 64);                     \
    } while (0)

    // prologue: stage step 0
    STAGE(As0, Bs0, 0);
    __syncthreads();

    char* curA = As0; char* nxtA = As1;
    char* curB = Bs0; char* nxtB = Bs1;

    #pragma unroll 1
    for (int k = 0; k < 4; k++) {
        const bool more = (k < 3);
        if (more) STAGE(nxtA, nxtB, k + 1);      // in flight across ~550 cyc

        __builtin_amdgcn_s_setprio(1);
        #pragma unroll
        for (int s = 0; s < 2; s++) {
            const int sb = s * 8192;
            union { uint4 u[2]; i32x8 v; } fa0, fa1, fb0, fb1;
            fa0.u[0] = *(const uint4*)(curA + sb + ra + p0);
            fa0.u[1] = *(const uint4*)(curA + sb + ra + p1);
            fa1.u[0] = *(const uint4*)(curA + sb + ra + 2048 + p0);
            fa1.u[1] = *(const uint4*)(curA + sb + ra + 2048 + p1);
            fb0.u[0] = *(const uint4*)(curB + sb + rb + p0);
            fb0.u[1] = *(const uint4*)(curB + sb + rb + p1);
            fb1.u[0] = *(const uint4*)(curB + sb + rb + 2048 + p0);
            fb1.u[1] = *(const uint4*)(curB + sb + rb + 2048 + p1);

            accv[0][0] = __builtin_amdgcn_mfma_scale_f32_32x32x64_f8f6f4(
                fa0.v, fb0.v, accv[0][0], 0, 0, 0, 0x7F7F7F7F, 0, 0x7F7F7F7F);
            accv[0][1] = __builtin_amdgcn_mfma_scale_f32_32x32x64_f8f6f4(
                fa0.v, fb1.v, accv[0][1], 0, 0, 0, 0x7F7F7F7F, 0, 0x7F7F7F7F);
            accv[1][0] = __builtin_amdgcn_mfma_scale_f32_32x32x64_f8f6f4(
                fa1.v, fb0.v, accv[1][0], 0, 0, 0, 0x7F7F7F7F, 0, 0x7F7F7F7F);
            accv[1][1] = __builtin_amdgcn_mfma_scale_f32_32x32x64_f8f6f4(
                fa1.v, fb1.v, accv[1][1], 0, 0, 0, 0x7F7F7F7F, 0, 0x7F7F7F7F);
        }
        __builtin_amdgcn_s_setprio(0);

        if (more) {
            __syncthreads();                     // drain hidden under compute
            char* tA = curA; curA = nxtA; nxtA = tA;
            char* tB = curB; curB = nxtB; nxtB = tB;
        }
    }
#undef STAGE

    // epilogue: term = exp(-0.1*sqrt(max(ni+nj-2*dot, 0))); diag -> 1
    // 32x32 C/D: col = lane&31, row = (reg&3) + 8*(reg>>2) + 4*(lane>>5)
    const float wgt = (bi == bj) ? 1.0f : 2.0f;
    const int cl = lane & 31;
    const int rh = (lane >> 5) * 4;
    float lsum = 0.0f;
    #pragma unroll
    for (int a = 0; a < 2; a++) {
        const int gia = rowA + wr + a * 32;
        float ni[16];
        #pragma unroll
        for (int r = 0; r < 16; r++)
            ni[r] = norms[gia + (r & 3) + 8 * (r >> 2) + rh];
        #pragma unroll
        for (int b = 0; b < 2; b++) {
            const int gj = rowB + wc + b * 32 + cl;
            const float nj = norms[gj];
            #pragma unroll
            for (int r = 0; r < 16; r++) {
                const int gi = gia + (r & 3) + 8 * (r >> 2) + rh;
                float sq = fmaf(-2.0f, accv[a][b][r], ni[r] + nj);
                sq = fmaxf(sq, 0.0f);
                float term = __expf(-0.1f * sqrtf(sq));
                if (gi == gj) term = 1.0f;
                lsum += term;
            }
        }
    }
    lsum *= wgt;
    #pragma unroll
    for (int off = 32; off > 0; off >>= 1) lsum += __shfl_down(lsum, off, 64);
    if (lane == 0) wsum[w] = lsum;
    __syncthreads();

    // fused finalize: last block to complete sums the NACC slots.
    // Ordering WITHOUT a device fence: the done-counter atomic is issued
    // only after this block's acc-RMW has returned (asm keeps the value
    // live -> s_waitcnt vmcnt before it; wave issue is in-order).
    if (tid == 0) {
        float bsum = wsum[0] + wsum[1] + wsum[2] + wsum[3];
        float old = atomicAdd(&acc[blockIdx.x & (NACC - 1)], bsum);
        asm volatile("" :: "v"(old));
        unsigned prev = atomicAdd((unsigned int*)(acc + NACC), 1u);
        lastflag = (prev == NTRI - 1) ? 1 : 0;
    }
    __syncthreads();
    if (lastflag && tid < 64) {
        float v = atomicAdd(&acc[tid], 0.0f);    // coherent read (device atomic)
        #pragma unroll
        for (int off = 32; off > 0; off >>= 1) v += __shfl_down(v, off, 64);
        if (tid == 0) {
            const float inv = 1.0f / ((float)NROWS * (float)NROWS); // 2^-26
            float loss = v * inv * 0.1f;
            out[0] = loss;
            out[1] = 0.5f * loss;
        }
    }
}

extern "C" void kernel_launch(void* const* d_in, const int* in_sizes, int n_in,
                              void* d_out, int out_size, void* d_ws, size_t ws_size,
                              hipStream_t stream)
{
    const float* X = (const float*)d_in[0];
    float* out = (float*)d_out;

    char* ws = (char*)d_ws;
    float*         acc   = (float*)ws;                   // NACC slots + counter
    float*         norms = (float*)(ws + 1024);          // 8192 fp32 (32 KB)
    unsigned char* Xq    = (unsigned char*)(ws + 1024 + 32768); // fp8 X, 4 MB

    norm_convert_kernel<<<NROWS / 4, 256, 0, stream>>>(X, Xq, norms, acc);
    pair_loss_gemm_kernel<<<NTRI, 256, 0, stream>>>(Xq, norms, acc, out);
}

// Round 4
// 109.533 us; speedup vs baseline: 1.0573x; 1.0573x over previous
//
#include <hip/hip_runtime.h>

// Problem constants
#define NROWS 8192   // 4 * 2048
#define DIM   512
#define NT    64                    // 8192 / 128 tiles per side
#define NTRI  (NT * (NT + 1) / 2)   // 2080 upper-triangular tile blocks
#define NACC  64                    // accumulator slots (contention spread)

typedef __attribute__((ext_vector_type(16))) float f32x16;
typedef __attribute__((ext_vector_type(8)))  int   i32x8;

// Software fp32 -> OCP e4m3fn, round-to-nearest-even (r7/r8-verified).
__device__ __forceinline__ unsigned char f2e4m3(float x) {
    unsigned ux = __float_as_uint(x);
    unsigned s  = (ux >> 24) & 0x80u;
    float a = __uint_as_float(ux & 0x7FFFFFFFu);     // |x|, finite for our data
    a = fminf(a, 448.0f);                            // clamp to max finite
    unsigned ua = __float_as_uint(a);
    int eb = (int)(ua >> 23);                        // biased exponent
    if (eb < 121) eb = 121;                          // denormal region: step 2^-9
    float step  = __uint_as_float((unsigned)(eb - 3) << 23);    // 2^(eb-130)
    float istep = __uint_as_float((unsigned)(257 - eb) << 23);  // 2^(130-eb), exact
    float q = rintf(a * istep) * step;               // RNE on e4m3 grid
    q = fminf(q, 448.0f);
    if (q < 0.001953125f)                            // below min denormal 2^-9 -> 0
        return (unsigned char)s;
    unsigned uq = __float_as_uint(q);
    int eq = (int)(uq >> 23) - 127;
    unsigned byte;
    if (eq < -6) byte = (unsigned)(q * 512.0f);      // denormal: d*2^-9, d in 1..7
    else         byte = (unsigned)((eq + 7) << 3) | ((uq >> 20) & 7u);
    return (unsigned char)(s | byte);
}

// Kernel 1: fp32 row norms + fp32->fp8 conversion into a pre-swizzled global
// layout (verified r1/r2): within each 64B k-slab of row r, 16B chunk c is
// stored at position c ^ ((r>>1)&3). GEMM staging is then a linear
// global_load_lds copy (rule #21); frag ds_read_b128s are at the bank floor.
__global__ __launch_bounds__(256) void norm_convert_kernel(
    const float* __restrict__ X, unsigned char* __restrict__ Xq,
    float* __restrict__ norms, float* __restrict__ acc)
{
    const int tid  = threadIdx.x;
    const int lane = tid & 63;
    const int w    = tid >> 6;
    const int row  = blockIdx.x * 4 + w;

    if (blockIdx.x == 0 && tid < NACC + 1) acc[tid] = 0.0f;  // +1: done-counter

    const float* xr = X + (size_t)row * DIM + lane * 8;
    float4 v0 = *(const float4*)xr;
    float4 v1 = *(const float4*)(xr + 4);

    float s = 0.0f;
    s = fmaf(v0.x, v0.x, s); s = fmaf(v0.y, v0.y, s);
    s = fmaf(v0.z, v0.z, s); s = fmaf(v0.w, v0.w, s);
    s = fmaf(v1.x, v1.x, s); s = fmaf(v1.y, v1.y, s);
    s = fmaf(v1.z, v1.z, s); s = fmaf(v1.w, v1.w, s);

    union { unsigned char b[8]; uint2 v; } pk;
    pk.b[0] = f2e4m3(v0.x); pk.b[1] = f2e4m3(v0.y);
    pk.b[2] = f2e4m3(v0.z); pk.b[3] = f2e4m3(v0.w);
    pk.b[4] = f2e4m3(v1.x); pk.b[5] = f2e4m3(v1.y);
    pk.b[6] = f2e4m3(v1.z); pk.b[7] = f2e4m3(v1.w);

    const int slab = lane >> 3;                      // 64B slab index (0..7)
    const int c16  = (lane >> 1) & 3;                // 16B chunk in slab
    const int cpos = c16 ^ ((row >> 1) & 3);         // swizzled chunk position
    *(uint2*)(Xq + (size_t)row * DIM + slab * 64 + cpos * 16 + (lane & 1) * 8)
        = pk.v;

    #pragma unroll
    for (int off = 32; off > 0; off >>= 1) s += __shfl_down(s, off, 64);
    if (lane == 0) norms[row] = s;
}

// Async global->LDS DMA, 16B/lane (dest = wave-uniform base + lane*16).
__device__ __forceinline__ void gload16(const void* g, void* l) {
    __builtin_amdgcn_global_load_lds(
        (const __attribute__((address_space(1))) unsigned int*)g,
        (__attribute__((address_space(3))) unsigned int*)l, 16, 0, 0);
}

// Kernel 2: upper-triangular tiled X·X^T (MX fp8, unit scales) + fused
// sqrt/exp/sum epilogue + fused last-block finalize.
//
// r12 = r11's counted-vmcnt schedule re-based onto the r0/r1-proven 128x128
// / 4-wave / 256-thread geometry (r11 container died; novel-risk axes were
// 96KB static LDS + 512 threads — both removed; schedule hypothesis kept):
//   - 3-slot LDS ring, 48KB static (3 x (8K A + 8K B)); 3 blocks/CU.
//   - ONE raw s_barrier per K-step; inline s_waitcnt vmcnt(4) (never 0
//     in-loop): own step-k loads (oldest 4) retired, STAGE(k+1)'s 4 fly.
//     STAGE(k+2) issued right after barrier(k): slot (k+2)%3 was last read
//     by compute(k-1), whose ds_reads retired before barrier(k) (lgkmcnt
//     waits precede MFMA use; in-order issue).
//   - prefetch depth 2: loads issued ~2 iterations (~1600+ cyc) before
//     use >> L3/HBM latency (~500-900 cyc; r2 FETCH 17MB >> 4MB input
//     shows staging mostly misses L2).
//   - T5 setprio around the MFMA cluster; sched_barrier(0) pins the
//     regions (rule #18 family).
// Data path (staging pattern, 16B swizzle, MX frag layout, C/D layout) is
// byte-identical to r1/r2 (absmax 0 twice).
// NO device-scope fences (r3: fence = per-XCD L2 flush, +40us).
__global__ __launch_bounds__(256, 3) void pair_loss_gemm_kernel(
    const unsigned char* __restrict__ Xq, const float* __restrict__ norms,
    float* __restrict__ acc, float* __restrict__ out)
{
    // ring slot: [A: 128 rows x 64B | B: 128 rows x 64B] = 16KB
    __shared__ __align__(16) char Ls[3][16384];
    __shared__ float wsum[4];
    __shared__ int lastflag;

    // XCD-aware remap (2080 = 8*260, bijective), then upper-tri decode
    const int bid = (blockIdx.x & 7) * 260 + (blockIdx.x >> 3);
    int t = bid, bi = 0;
    while (t >= (NT - bi)) { t -= (NT - bi); bi++; }
    const int bj = bi + t;

    const int tid  = threadIdx.x;
    const int lane = tid & 63;
    const int w    = tid >> 6;          // 0..3

    const int rowA = bi * 128;
    const int rowB = bj * 128;

    f32x16 accv[2][2];
    #pragma unroll
    for (int a = 0; a < 2; a++)
        #pragma unroll
        for (int b = 0; b < 2; b++)
            #pragma unroll
            for (int r = 0; r < 16; r++) accv[a][b][r] = 0.0f;

    // staging: wave w stages rows [w*32, w*32+32) of A and B.
    // Per gload16: 16 rows; lane -> row lane>>2, 16B chunk lane&3 at
    // swizzled global pos (lane&3)^((lane>>3)&3) (base rows mult of 16).
    const int lrow = lane >> 2;
    const int lpos = ((lane & 3) ^ ((lane >> 3) & 3)) * 16;
    const unsigned char* gA0 = Xq + (size_t)(rowA + w * 32 + lrow) * DIM + lpos;
    const unsigned char* gA1 = gA0 + (size_t)16 * DIM;
    const unsigned char* gB0 = Xq + (size_t)(rowB + w * 32 + lrow) * DIM + lpos;
    const unsigned char* gB1 = gB0 + (size_t)16 * DIM;
    const int dst0 = (w * 32) * 64;
    const int dst1 = (w * 32 + 16) * 64;

    // MFMA frag addressing (r1/r2-verified): row rl = lane&31, k-half
    // qh = lane>>5 -> 16B chunks {2qh, 2qh^1} at swizzled pos ^((rl>>1)&3).
    const int rl = lane & 31;
    const int qh = lane >> 5;
    const int p0 = ((2 * qh) ^ ((rl >> 1) & 3)) * 16;
    const int p1 = p0 ^ 16;
    const int wr = (w & 1) * 64;
    const int wc = (w >> 1) * 64;
    const int ra = (wr + rl) * 64;                   // a=0 row offset (A half)
    const int rb = 8192 + (wc + rl) * 64;            // b=0 row offset (B half)

#define STAGE(s) do {                                                    \
        char* sl_ = Ls[(s) % 3];                                         \
        const int kb_ = (s) * 64;                                        \
        gload16(gA0 + kb_, sl_ + dst0);                                  \
        gload16(gA1 + kb_, sl_ + dst1);                                  \
        gload16(gB0 + kb_, sl_ + 8192 + dst0);                           \
        gload16(gB1 + kb_, sl_ + 8192 + dst1);                           \
    } while (0)

    // prologue: steps 0,1 in flight (depth 2)
    STAGE(0);
    STAGE(1);

    #pragma unroll
    for (int k = 0; k < 8; k++) {
        __builtin_amdgcn_sched_barrier(0);
        // counted wait: own step-k loads (oldest 4) done; newer may fly
        if (k < 7) asm volatile("s_waitcnt vmcnt(4)" ::: "memory");
        else       asm volatile("s_waitcnt vmcnt(0)" ::: "memory");
        __builtin_amdgcn_s_barrier();            // raw: no compiler drain
        __builtin_amdgcn_sched_barrier(0);

        if (k < 6) STAGE(k + 2);                 // slot freed at this barrier

        const char* sl = Ls[k % 3];
        union frag { uint4 u[2]; i32x8 v; };
        frag fa0, fa1, fb0, fb1;
        fa0.u[0] = *(const uint4*)(sl + ra + p0);
        fa0.u[1] = *(const uint4*)(sl + ra + p1);
        fa1.u[0] = *(const uint4*)(sl + ra + 2048 + p0);
        fa1.u[1] = *(const uint4*)(sl + ra + 2048 + p1);
        fb0.u[0] = *(const uint4*)(sl + rb + p0);
        fb0.u[1] = *(const uint4*)(sl + rb + p1);
        fb1.u[0] = *(const uint4*)(sl + rb + 2048 + p0);
        fb1.u[1] = *(const uint4*)(sl + rb + 2048 + p1);

        __builtin_amdgcn_s_setprio(1);
        accv[0][0] = __builtin_amdgcn_mfma_scale_f32_32x32x64_f8f6f4(
            fa0.v, fb0.v, accv[0][0], 0, 0, 0, 0x7F7F7F7F, 0, 0x7F7F7F7F);
        accv[0][1] = __builtin_amdgcn_mfma_scale_f32_32x32x64_f8f6f4(
            fa0.v, fb1.v, accv[0][1], 0, 0, 0, 0x7F7F7F7F, 0, 0x7F7F7F7F);
        accv[1][0] = __builtin_amdgcn_mfma_scale_f32_32x32x64_f8f6f4(
            fa1.v, fb0.v, accv[1][0], 0, 0, 0, 0x7F7F7F7F, 0, 0x7F7F7F7F);
        accv[1][1] = __builtin_amdgcn_mfma_scale_f32_32x32x64_f8f6f4(
            fa1.v, fb1.v, accv[1][1], 0, 0, 0, 0x7F7F7F7F, 0, 0x7F7F7F7F);
        __builtin_amdgcn_s_setprio(0);
        __builtin_amdgcn_sched_barrier(0);
    }
#undef STAGE

    // epilogue: term = exp(-0.1*sqrt(max(ni+nj-2*dot, 0))); diag -> 1
    // 32x32 C/D: col = lane&31, row = (reg&3) + 8*(reg>>2) + 4*(lane>>5)
    const float wgt = (bi == bj) ? 1.0f : 2.0f;
    const int cl = lane & 31;
    const int rh = qh * 4;
    float lsum = 0.0f;
    #pragma unroll
    for (int a = 0; a < 2; a++) {
        const int gia = rowA + wr + a * 32;
        float ni[16];
        #pragma unroll
        for (int r = 0; r < 16; r++)
            ni[r] = norms[gia + (r & 3) + 8 * (r >> 2) + rh];
        #pragma unroll
        for (int b = 0; b < 2; b++) {
            const int gj = rowB + wc + b * 32 + cl;
            const float nj = norms[gj];
            #pragma unroll
            for (int r = 0; r < 4; r++) {
                // unrolled by compiler; keep flat 16-reg walk
            }
            #pragma unroll
            for (int r = 0; r < 16; r++) {
                const int gi = gia + (r & 3) + 8 * (r >> 2) + rh;
                float sq = fmaf(-2.0f, accv[a][b][r], ni[r] + nj);
                sq = fmaxf(sq, 0.0f);
                float term = __expf(-0.1f * sqrtf(sq));
                if (gi == gj) term = 1.0f;
                lsum += term;
            }
        }
    }
    lsum *= wgt;
    #pragma unroll
    for (int off = 32; off > 0; off >>= 1) lsum += __shfl_down(lsum, off, 64);
    if (lane == 0) wsum[w] = lsum;
    __syncthreads();

    // fused finalize (r2-verified): last block sums the NACC slots.
    // Ordering WITHOUT a device fence: done-counter atomic issued only after
    // this block's acc-RMW returned (asm keeps value live; in-order issue).
    if (tid == 0) {
        float bsum = wsum[0] + wsum[1] + wsum[2] + wsum[3];
        float old = atomicAdd(&acc[bid & (NACC - 1)], bsum);
        asm volatile("" :: "v"(old));
        unsigned prev = atomicAdd((unsigned int*)(acc + NACC), 1u);
        lastflag = (prev == NTRI - 1) ? 1 : 0;
    }
    __syncthreads();
    if (lastflag && tid < 64) {
        float v = atomicAdd(&acc[tid], 0.0f);    // coherent read (device atomic)
        #pragma unroll
        for (int off = 32; off > 0; off >>= 1) v += __shfl_down(v, off, 64);
        if (tid == 0) {
            const float inv = 1.0f / ((float)NROWS * (float)NROWS); // 2^-26
            float loss = v * inv * 0.1f;
            out[0] = loss;
            out[1] = 0.5f * loss;
        }
    }
}

extern "C" void kernel_launch(void* const* d_in, const int* in_sizes, int n_in,
                              void* d_out, int out_size, void* d_ws, size_t ws_size,
                              hipStream_t stream)
{
    const float* X = (const float*)d_in[0];
    float* out = (float*)d_out;

    char* ws = (char*)d_ws;
    float*         acc   = (float*)ws;                   // NACC slots + counter
    float*         norms = (float*)(ws + 1024);          // 8192 fp32 (32 KB)
    unsigned char* Xq    = (unsigned char*)(ws + 1024 + 32768); // fp8 X, 4 MB

    norm_convert_kernel<<<NROWS / 4, 256, 0, stream>>>(X, Xq, norms, acc);
    pair_loss_gemm_kernel<<<NTRI, 256, 0, stream>>>(Xq, norms, acc, out);
}